// Round 11
// baseline (589.625 us; speedup 1.0000x reference)
//
#include <hip/hip_runtime.h>

typedef _Float16 f16;
typedef _Float16 f16x8 __attribute__((ext_vector_type(8)));
typedef _Float16 f16x4 __attribute__((ext_vector_type(4)));
typedef float    f32x4 __attribute__((ext_vector_type(4)));

#define H  128
#define G3 384
#define AH 36
#define PADW 136   // padded LDS row: 136 f16 = 272B

// v_rcp_f32 (~1 ulp) — proven R10: IEEE div was the hidden VALU bloat.
__device__ __forceinline__ float sigmoidf_(float x){
  return __builtin_amdgcn_rcpf(1.f + __expf(-x));
}
__device__ __forceinline__ float tanhf_(float x){
  return fmaf(2.f, __builtin_amdgcn_rcpf(1.f + __expf(-2.f*x)), -1.f);
}

// LDS-only barrier: global prefetch loads stay in flight across it.
__device__ __forceinline__ void lds_sync(){
  asm volatile("s_waitcnt lgkmcnt(0)" ::: "memory");
  __builtin_amdgcn_s_barrier();
  asm volatile("" ::: "memory");
}

// ---------------- prep ----------------
__global__ void prep_weights(const float* __restrict__ a, const float* __restrict__ b,
                             const float* __restrict__ c, const float* __restrict__ d,
                             f16* __restrict__ dst)
{
  int i = blockIdx.x * 256 + threadIdx.x;
  if (i >= 4 * G3 * H) return;
  int m = i / (G3 * H), j = i % (G3 * H);
  const float* s = (m == 0) ? a : (m == 1) ? b : (m == 2) ? c : d;
  dst[i] = (f16)s[j];
}

__global__ void prep_len(const int* __restrict__ mask, int* __restrict__ len, int T, int B)
{
  int b = blockIdx.x * 256 + threadIdx.x;
  if (b >= B) return;
  int s = 0;
  for (int t = 0; t < T; ++t) s += (mask[(size_t)b * T + t] > 0);
  len[b] = s;
}

// bulk f32 -> f16 convert (memory-bound, ~15us)
__global__ __launch_bounds__(256)
void prep_cvt(const float* __restrict__ src, f16* __restrict__ dst, int n8)
{
  int i = blockIdx.x * 256 + threadIdx.x;
  const int stride = gridDim.x * 256;
  for (; i < n8; i += stride) {
    f32x4 a = *(const f32x4*)(src + (size_t)i * 8);
    f32x4 b = *(const f32x4*)(src + (size_t)i * 8 + 4);
    f16x8 o = {(f16)a.x,(f16)a.y,(f16)a.z,(f16)a.w,(f16)b.x,(f16)b.y,(f16)b.z,(f16)b.w};
    *(f16x8*)(dst + (size_t)i * 8) = o;
  }
}

// ---------------- fused GRU / AUGRU scan (v8: pipelined x-GEMM, reg x-frags) ----------------
// Post-barrier critical path: ds_read h -> 4-deep MFMA chain -> gates -> ds_write h.
// x-side GEMM for step t+1 runs during step t (aXr/aXz/aXn carried in regs,
// biases folded as C-init). x B-frags loaded straight from global (depth-2).
template<bool AUG>
__global__ __launch_bounds__(512)
__attribute__((amdgpu_waves_per_eu(2, 2)))
void scan_kernel(const f16*   __restrict__ xin,   // [B,T,H] f16 (ub_f16 or hist)
                 const f16*   __restrict__ Wih,   // [3H][H] f16
                 const f16*   __restrict__ Whh,   // [3H][H] f16
                 const float* __restrict__ bih,
                 const float* __restrict__ bhh,
                 const float* __restrict__ att,   // [B,T] (AUG)
                 const int*   __restrict__ len,   // [B]   (AUG)
                 f16*         __restrict__ histo, // [B,T,H] f16 (GRU)
                 float*       __restrict__ outp,  // [B,H]       (AUG)
                 int T)
{
  __shared__ f16 hs[2][16 * PADW];

  const int tid = threadIdx.x;
  const int w   = tid >> 6;
  const int l   = tid & 63;
  const int l16 = l & 15;
  const int lhi = l >> 4;
  const int b0  = blockIdx.x * 16;
  const int colb = w * 16;
  const int c4   = colb + lhi * 4;
  const int srow = tid >> 5, cc = tid & 31;

  // Weight fragments (24 x f16x8 = 96 regs), pinned.
  f16x8 wih[3][4], whh[3][4];
  #pragma unroll
  for (int g = 0; g < 3; ++g)
    #pragma unroll
    for (int q = 0; q < 4; ++q) {
      int off = (g * H + colb + l16) * H + q * 32 + lhi * 8;
      wih[g][q] = *(const f16x8*)(Wih + off);
      whh[g][q] = *(const f16x8*)(Whh + off);
    }
  #pragma unroll
  for (int g = 0; g < 3; ++g)
    #pragma unroll
    for (int q = 0; q < 4; ++q)
      asm volatile("" : "+v"(wih[g][q]), "+v"(whh[g][q]));

  // bias C-inits
  f32x4 bRs = *(const f32x4*)(bih + c4);
  { f32x4 t2 = *(const f32x4*)(bhh + c4);     bRs += t2; }
  f32x4 bZs = *(const f32x4*)(bih + H + c4);
  { f32x4 t2 = *(const f32x4*)(bhh + H + c4); bZs += t2; }
  f32x4 bXn = *(const f32x4*)(bih + 2*H + c4);
  f32x4 bHn = *(const f32x4*)(bhh + 2*H + c4);

  float hold[4] = {0.f, 0.f, 0.f, 0.f};
  int len_l = 0;
  if (AUG) len_l = len[b0 + l16];

  // LDS pointers (h double buffer only)
  const f16* hrd0 = &hs[0][l16 * PADW + lhi * 8];   // + q*32 at use
  const f16* hrd1 = &hs[1][l16 * PADW + lhi * 8];
  f16* hwr0 = &hs[0][l16 * PADW + c4];
  f16* hwr1 = &hs[1][l16 * PADW + c4];

  // global pointers
  const f16*   pxF  = xin + ((size_t)(b0 + l16) * T) * H + lhi * 8;  // wave-shared x frags
  const float* attB = AUG ? (att + (size_t)(b0 + l16) * T) : nullptr;
  f16*         histp = (!AUG && histo) ? (histo + ((size_t)(b0 + l16) * T) * H + c4) : nullptr;
  float*       outpp = AUG ? (outp + (size_t)(b0 + l16) * H + c4) : nullptr;

  // prologue: zero h buf0; x-GEMM for t=0; frags for t=1; att
  {
    f16x4 z4 = {(f16)0, (f16)0, (f16)0, (f16)0};
    *(f16x4*)(&hs[0][srow * PADW + cc * 4]) = z4;
  }
  f32x4 aXr, aXz, aXn_;
  {
    f16x8 xb0[4];
    #pragma unroll
    for (int q = 0; q < 4; ++q) xb0[q] = *(const f16x8*)(pxF + q * 32);
    aXr = bRs; aXz = bZs; aXn_ = bXn;
    #pragma unroll
    for (int q = 0; q < 4; ++q) {
      aXr  = __builtin_amdgcn_mfma_f32_16x16x32_f16(wih[0][q], xb0[q], aXr, 0,0,0);
      aXz  = __builtin_amdgcn_mfma_f32_16x16x32_f16(wih[1][q], xb0[q], aXz, 0,0,0);
      aXn_ = __builtin_amdgcn_mfma_f32_16x16x32_f16(wih[2][q], xb0[q], aXn_,0,0,0);
    }
  }
  f16x8 xbA[4], xbB[4];
  if (T > 1) {
    #pragma unroll
    for (int q = 0; q < 4; ++q) xbA[q] = *(const f16x8*)(pxF + H + q * 32);
  }
  pxF += 2 * H;                         // points at t=2
  float Aa = 0.f, Ab = 0.f;
  if (AUG) {
    Aa = attB[0];
    if (T > 1) Ab = attB[1];
  }
  lds_sync();

// XBW: frags for t+1 (ready, consumed by pipelined x-GEMM)
// XBL: load target for t+2 frags. Names suffixed (R3 lesson).
#define STEP(targ_, XBW, XBL, HRD, HWRN, AW)                                   \
  {                                                                            \
    const int t5_ = (targ_);                                                   \
    float at_ = 0.f;                                                           \
    if (AUG) at_ = AW;                                                         \
    if (t5_ + 2 < T) {                                                         \
      _Pragma("unroll")                                                        \
      for (int q = 0; q < 4; ++q) XBL[q] = *(const f16x8*)(pxF + q * 32);      \
      if (AUG) AW = attB[t5_ + 2];                                             \
    }                                                                          \
    pxF += H;                                                                  \
    f16x8 hb[4];                                                               \
    _Pragma("unroll")                                                          \
    for (int q = 0; q < 4; ++q) hb[q] = *(const f16x8*)(HRD + q * 32);         \
    f32x4 aR = aXr, aZ = aXz, aN = bHn;                                        \
    _Pragma("unroll")                                                          \
    for (int q = 0; q < 4; ++q) {                                              \
      aR = __builtin_amdgcn_mfma_f32_16x16x32_f16(whh[0][q], hb[q], aR, 0,0,0);\
      aZ = __builtin_amdgcn_mfma_f32_16x16x32_f16(whh[1][q], hb[q], aZ, 0,0,0);\
      aN = __builtin_amdgcn_mfma_f32_16x16x32_f16(whh[2][q], hb[q], aN, 0,0,0);\
    }                                                                          \
    float hn_[4];                                                              \
    _Pragma("unroll")                                                          \
    for (int i = 0; i < 4; ++i) {                                              \
      float r = sigmoidf_(aR[i]);                                              \
      float z = sigmoidf_(aZ[i]);                                              \
      float n = tanhf_(aXn_[i] + r * aN[i]);                                   \
      float h;                                                                 \
      if (AUG) { float u = z * at_; h = hold[i] + u * (n - hold[i]); }         \
      else     { h = n + z * (hold[i] - n); }                                  \
      hold[i] = h; hn_[i] = h;                                                 \
    }                                                                          \
    f16x4 hv = {(f16)hn_[0], (f16)hn_[1], (f16)hn_[2], (f16)hn_[3]};           \
    *(f16x4*)(HWRN) = hv;                                                      \
    if (!AUG) {                                                                \
      *(f16x4*)histp = hv;  histp += H;                                        \
    } else {                                                                   \
      if (t5_ == len_l - 1) {                                                  \
        f32x4 ov = {hn_[0], hn_[1], hn_[2], hn_[3]};                           \
        *(f32x4*)outpp = ov;                                                   \
      }                                                                        \
    }                                                                          \
    if (t5_ + 1 < T) {                                                         \
      aXr = bRs; aXz = bZs; aXn_ = bXn;                                        \
      _Pragma("unroll")                                                        \
      for (int q = 0; q < 4; ++q) {                                            \
        aXr  = __builtin_amdgcn_mfma_f32_16x16x32_f16(wih[0][q], XBW[q], aXr, 0,0,0);  \
        aXz  = __builtin_amdgcn_mfma_f32_16x16x32_f16(wih[1][q], XBW[q], aXz, 0,0,0);  \
        aXn_ = __builtin_amdgcn_mfma_f32_16x16x32_f16(wih[2][q], XBW[q], aXn_,0,0,0);  \
      }                                                                        \
    }                                                                          \
    lds_sync();                                                                \
  }

  for (int t = 0; t < T; t += 2) {
    STEP(t,     xbA, xbB, hrd0, hwr1, Aa)
    STEP(t + 1, xbB, xbA, hrd1, hwr0, Ab)
  }
#undef STEP
}

// ---------------- DIN attention (MFMA version; rcp sigmoid — R10) ----------------
__global__ __launch_bounds__(256)
void attn_kernel(const float* __restrict__ query,
                 const f16*   __restrict__ hist,
                 const int*   __restrict__ mask,
                 const float* __restrict__ W1, const float* __restrict__ b1,
                 const float* __restrict__ W2, const float* __restrict__ b2,
                 float* __restrict__ attv, int T)
{
  __shared__ float qs[H];
  __shared__ f16   WqH[48 * PADW];
  __shared__ float qcp[48], w2p[48];
  __shared__ float logitsS[224];
  __shared__ float red[256];

  const int tid = threadIdx.x, b = blockIdx.x;
  const int w = tid >> 6, l = tid & 63, l16 = l & 15, lhi = l >> 4;

  if (tid < H) qs[tid] = query[b * H + tid];
  if (tid < 48) w2p[tid] = (tid < AH) ? W2[tid] : 0.f;
  __syncthreads();

  for (int i = tid; i < 48 * H; i += 256) {
    int u = i >> 7, k = i & (H - 1);
    float v = 0.f;
    if (u < AH) {
      const float* r = W1 + u * 4 * H;
      v = r[H + k] - r[2*H + k] + qs[k] * r[3*H + k];
    }
    WqH[u * PADW + k] = (f16)v;
  }
  if (tid < 48) {
    float s = 0.f;
    if (tid < AH) {
      const float* r = W1 + tid * 4 * H;
      s = b1[tid];
      for (int k = 0; k < H; ++k) s += qs[k] * (r[k] + r[2*H + k]);
    }
    qcp[tid] = s;
  }
  __syncthreads();

  const f32x4 qcv0 = *(const f32x4*)&qcp[lhi*4];
  const f32x4 qcv1 = *(const f32x4*)&qcp[16 + lhi*4];
  const f32x4 qcv2 = *(const f32x4*)&qcp[32 + lhi*4];
  const f32x4 w2v0 = *(const f32x4*)&w2p[lhi*4];
  const f32x4 w2v1 = *(const f32x4*)&w2p[16 + lhi*4];
  const f32x4 w2v2 = *(const f32x4*)&w2p[32 + lhi*4];

  const int NMT = (T + 15) >> 4;
  for (int mt = w; mt < NMT; mt += 4) {
    const int t0 = mt * 16;
    f16x8 hbf[4];
    #pragma unroll
    for (int q = 0; q < 4; ++q)
      hbf[q] = *(const f16x8*)(hist + ((size_t)b*T + t0 + l16)*H + q*32 + lhi*8);
    f32x4 d0 = {0,0,0,0}, d1 = {0,0,0,0}, d2 = {0,0,0,0};
    #pragma unroll
    for (int q = 0; q < 4; ++q) {
      f16x8 wq0 = *(const f16x8*)(&WqH[ l16       * PADW + q*32 + lhi*8]);
      f16x8 wq1 = *(const f16x8*)(&WqH[(16 + l16) * PADW + q*32 + lhi*8]);
      f16x8 wq2 = *(const f16x8*)(&WqH[(32 + l16) * PADW + q*32 + lhi*8]);
      d0 = __builtin_amdgcn_mfma_f32_16x16x32_f16(wq0, hbf[q], d0, 0,0,0);
      d1 = __builtin_amdgcn_mfma_f32_16x16x32_f16(wq1, hbf[q], d1, 0,0,0);
      d2 = __builtin_amdgcn_mfma_f32_16x16x32_f16(wq2, hbf[q], d2, 0,0,0);
    }
    float p = 0.f;
    #pragma unroll
    for (int i = 0; i < 4; ++i) {
      p += w2v0[i] * sigmoidf_(d0[i] + qcv0[i]);
      p += w2v1[i] * sigmoidf_(d1[i] + qcv1[i]);
      p += w2v2[i] * sigmoidf_(d2[i] + qcv2[i]);
    }
    p += __shfl_xor(p, 16, 64);
    p += __shfl_xor(p, 32, 64);
    if (lhi == 0) logitsS[t0 + l16] = p;
  }
  __syncthreads();

  const int t = tid;
  float logit = -1e30f; int mk = 0;
  if (t < T) {
    mk = mask[(size_t)b*T + t];
    logit = (mk > 0) ? (logitsS[t] + b2[0]) : -1e30f;
  }
  red[tid] = logit; __syncthreads();
  for (int s = 128; s > 0; s >>= 1) { if (tid < s) red[tid] = fmaxf(red[tid], red[tid+s]); __syncthreads(); }
  float mx = red[0]; __syncthreads();
  float ev = (t < T && mk > 0) ? __expf(logit - mx) : 0.f;
  red[tid] = ev; __syncthreads();
  for (int s = 128; s > 0; s >>= 1) { if (tid < s) red[tid] += red[tid+s]; __syncthreads(); }
  float sm = red[0];
  if (t < T) attv[(size_t)b*T + t] = ev * __builtin_amdgcn_rcpf(sm);
}

// ---------------- host ----------------
extern "C" void kernel_launch(void* const* d_in, const int* in_sizes, int n_in,
                              void* d_out, int out_size, void* d_ws, size_t ws_size,
                              hipStream_t stream)
{
  const float* query = (const float*)d_in[0];
  const float* ub    = (const float*)d_in[1];
  const int*   mask  = (const int*)d_in[2];
  const float* gWih  = (const float*)d_in[3];
  const float* gWhh  = (const float*)d_in[4];
  const float* gbih  = (const float*)d_in[5];
  const float* gbhh  = (const float*)d_in[6];
  const float* aW1   = (const float*)d_in[7];
  const float* ab1   = (const float*)d_in[8];
  const float* aW2   = (const float*)d_in[9];
  const float* ab2   = (const float*)d_in[10];
  const float* uWih  = (const float*)d_in[11];
  const float* uWhh  = (const float*)d_in[12];
  const float* ubih  = (const float*)d_in[13];
  const float* ubhh  = (const float*)d_in[14];

  const int B = in_sizes[0] / H;            // 1024
  const int T = in_sizes[1] / in_sizes[0];  // 200

  // workspace layout
  char*  ws    = (char*)d_ws;
  f16*   wf    = (f16*)ws;                                  // 393216 B
  int*   lenp  = (int*)(ws + 393216);                       // 4096 B
  float* attb  = (float*)(ws + 397312);                     // B*T*4 = 819200
  f16*   hist  = (f16*)(ws + 1216512);                      // B*T*H*2 = 52428800
  f16*   ubf16 = (f16*)(ws + 1216512 + 52428800);           // B*T*H*2 = 52428800

  prep_weights<<<(4 * G3 * H + 255) / 256, 256, 0, stream>>>(gWih, gWhh, uWih, uWhh, wf);
  prep_len<<<(B + 255) / 256, 256, 0, stream>>>(mask, lenp, T, B);
  prep_cvt<<<2048, 256, 0, stream>>>(ub, ubf16, B * T * H / 8);

  scan_kernel<false><<<B / 16, 512, 0, stream>>>(
      ubf16, wf, wf + G3 * H, gbih, gbhh,
      (const float*)nullptr, (const int*)nullptr, hist, (float*)nullptr, T);

  attn_kernel<<<B, 256, 0, stream>>>(query, hist, mask, aW1, ab1, aW2, ab2, attb, T);

  scan_kernel<true><<<B / 16, 512, 0, stream>>>(
      hist, wf + 2 * G3 * H, wf + 3 * G3 * H, ubih, ubhh,
      attb, lenp, (f16*)nullptr, (float*)d_out, T);
}

// Round 12
// 377.807 us; speedup vs baseline: 1.5607x; 1.5607x over previous
//
#include <hip/hip_runtime.h>

typedef _Float16 f16;
typedef _Float16 f16x8 __attribute__((ext_vector_type(8)));
typedef _Float16 f16x4 __attribute__((ext_vector_type(4)));
typedef float    f32x4 __attribute__((ext_vector_type(4)));

#define H  128
#define G3 384
#define AH 36
#define PADW 136   // padded LDS row: 136 f16 = 272B

// v_rcp_f32 (~1 ulp) — proven R10: IEEE div was the hidden VALU bloat.
__device__ __forceinline__ float sigmoidf_(float x){
  return __builtin_amdgcn_rcpf(1.f + __expf(-x));
}
__device__ __forceinline__ float tanhf_(float x){
  return fmaf(2.f, __builtin_amdgcn_rcpf(1.f + __expf(-2.f*x)), -1.f);
}

// LDS-only barrier: global prefetch loads stay in flight across it.
__device__ __forceinline__ void lds_sync(){
  asm volatile("s_waitcnt lgkmcnt(0)" ::: "memory");
  __builtin_amdgcn_s_barrier();
  asm volatile("" ::: "memory");
}

// ---------------- prep: weights fp32 -> fp16, lengths ----------------
__global__ void prep_weights(const float* __restrict__ a, const float* __restrict__ b,
                             const float* __restrict__ c, const float* __restrict__ d,
                             f16* __restrict__ dst)
{
  int i = blockIdx.x * 256 + threadIdx.x;
  if (i >= 4 * G3 * H) return;
  int m = i / (G3 * H), j = i % (G3 * H);
  const float* s = (m == 0) ? a : (m == 1) ? b : (m == 2) ? c : d;
  dst[i] = (f16)s[j];
}

__global__ void prep_len(const int* __restrict__ mask, int* __restrict__ len, int T, int B)
{
  int b = blockIdx.x * 256 + threadIdx.x;
  if (b >= B) return;
  int s = 0;
  for (int t = 0; t < T; ++t) s += (mask[(size_t)b * T + t] > 0);
  len[b] = s;
}

// ---------------- fused GRU / AUGRU scan (v9: R10 + split chains + staged gates) ----------------
template<bool AUG>
__global__ __launch_bounds__(512)
__attribute__((amdgpu_waves_per_eu(2, 2)))
void scan_kernel(const float* __restrict__ xf32,  // GRU input  [B,T,H] f32
                 const f16*   __restrict__ xf16,  // AUGRU input (hist) [B,T,H] f16
                 const f16*   __restrict__ Wih,   // [3H][H] f16
                 const f16*   __restrict__ Whh,   // [3H][H] f16
                 const float* __restrict__ bih,
                 const float* __restrict__ bhh,
                 const float* __restrict__ att,   // [B,T] (AUG)
                 const int*   __restrict__ len,   // [B]   (AUG)
                 f16*         __restrict__ histo, // [B,T,H] f16 (GRU)
                 float*       __restrict__ outp,  // [B,H]       (AUG)
                 int T)
{
  __shared__ f16  xs[2][16 * PADW];
  __shared__ f16  hs[2][16 * PADW];

  const int tid = threadIdx.x;
  const int w   = tid >> 6;
  const int l   = tid & 63;
  const int l16 = l & 15;
  const int lhi = l >> 4;
  const int b0  = blockIdx.x * 16;
  const int colb = w * 16;
  const int c4   = colb + lhi * 4;
  const int srow = tid >> 5, cc = tid & 31;

  // Weight fragments (24 x f16x8 = 96 regs), pinned.
  f16x8 wih[3][4], whh[3][4];
  #pragma unroll
  for (int g = 0; g < 3; ++g)
    #pragma unroll
    for (int q = 0; q < 4; ++q) {
      int off = (g * H + colb + l16) * H + q * 32 + lhi * 8;
      wih[g][q] = *(const f16x8*)(Wih + off);
      whh[g][q] = *(const f16x8*)(Whh + off);
    }
  #pragma unroll
  for (int g = 0; g < 3; ++g)
    #pragma unroll
    for (int q = 0; q < 4; ++q)
      asm volatile("" : "+v"(wih[g][q]), "+v"(whh[g][q]));

  // bias C-inits (x-chain carries the bias; h-chain starts at 0 except N)
  f32x4 bRs = *(const f32x4*)(bih + c4);
  { f32x4 t2 = *(const f32x4*)(bhh + c4);     bRs += t2; }
  f32x4 bZs = *(const f32x4*)(bih + H + c4);
  { f32x4 t2 = *(const f32x4*)(bhh + H + c4); bZs += t2; }
  f32x4 bXn = *(const f32x4*)(bih + 2*H + c4);
  f32x4 bHn = *(const f32x4*)(bhh + 2*H + c4);

  float hold[4] = {0.f, 0.f, 0.f, 0.f};
  int len_l = 0;
  if (AUG) len_l = len[b0 + l16];

  // hoisted LDS pointers
  const f16* xrd0 = &xs[0][l16 * PADW + lhi * 8];
  const f16* xrd1 = &xs[1][l16 * PADW + lhi * 8];
  const f16* hrd0 = &hs[0][l16 * PADW + lhi * 8];
  const f16* hrd1 = &hs[1][l16 * PADW + lhi * 8];
  f16* hwr0 = &hs[0][l16 * PADW + c4];
  f16* hwr1 = &hs[1][l16 * PADW + c4];
  f16* xst0 = &xs[0][srow * PADW + cc * 4];
  f16* xst1 = &xs[1][srow * PADW + cc * 4];

  // running global pointers
  const float* pxA32 = xf32 ? (xf32 + ((size_t)(b0 + srow) * T) * H + cc * 4) : nullptr;
  const f16*   pxA16 = xf16 ? (xf16 + ((size_t)(b0 + srow) * T) * H + cc * 4) : nullptr;
  const float* attB  = AUG ? (att + (size_t)(b0 + l16) * T) : nullptr;
  f16*         histp = (!AUG && histo) ? (histo + ((size_t)(b0 + l16) * T) * H + c4) : nullptr;
  float*       outpp = AUG ? (outp + (size_t)(b0 + l16) * H + c4) : nullptr;

  // prologue: zero h buf 0, stage x_0, prefetch x_1 into Pa
  {
    f16x4 z4 = {(f16)0, (f16)0, (f16)0, (f16)0};
    *(f16x4*)(&hs[0][srow * PADW + cc * 4]) = z4;
    if (AUG) {
      f16x4 v = *(const f16x4*)(pxA16);
      *(f16x4*)xst0 = v;
    } else {
      f32x4 v = *(const f32x4*)(pxA32);
      f16x4 h4 = {(f16)v.x, (f16)v.y, (f16)v.z, (f16)v.w};
      *(f16x4*)xst0 = h4;
    }
  }
  f32x4 Pa32 = {0,0,0,0}, Pb32 = {0,0,0,0};
  f16x4 Pa16 = {(f16)0,(f16)0,(f16)0,(f16)0}, Pb16 = Pa16;
  float Aa = 0.f, Ab = 0.f;
  if (AUG) {
    Pa16 = *(const f16x4*)(pxA16 + H);
    Aa = attB[0];
    if (T > 1) Ab = attB[1];
  } else {
    Pa32 = *(const f32x4*)(pxA32 + H);
  }
  const float* pxE32 = pxA32 ? pxA32 + 2 * H : nullptr;
  const float* pxO32 = pxA32 ? pxA32 + 3 * H : nullptr;
  const f16*   pxE16 = pxA16 ? pxA16 + 2 * H : nullptr;
  const f16*   pxO16 = pxA16 ? pxA16 + 3 * H : nullptr;
  lds_sync();

// Gate staging: Z MFMAs -> z sigmoid -> R MFMAs -> r sigmoid -> N MFMAs -> n.
// x/h chains split (depth 4 each) and merged with one f32x4 add.
#define STEP(targ_, XRD, HRD, HWRN, XSTN, PW32, PL32, PW16, PL16, AW, PXP32, PXP16) \
  {                                                                            \
    const int t5_  = (targ_);                                                  \
    float at_ = 0.f;                                                           \
    if (AUG) at_ = AW;                                                         \
    if (t5_ + 2 < T) {                                                         \
      if (AUG) {                                                               \
        PL16 = *(const f16x4*)(PXP16);  PXP16 += 2 * H;                        \
        AW = attB[t5_ + 2];                                                    \
      } else {                                                                 \
        PL32 = *(const f32x4*)(PXP32);  PXP32 += 2 * H;                        \
      }                                                                        \
    }                                                                          \
    f16x8 xb[4], hb[4];                                                        \
    _Pragma("unroll")                                                          \
    for (int q = 0; q < 4; ++q) {                                              \
      xb[q] = *(const f16x8*)(XRD + q * 32);                                   \
      hb[q] = *(const f16x8*)(HRD + q * 32);                                   \
    }                                                                          \
    f32x4 aZx = bZs, aZh = {0,0,0,0};                                          \
    _Pragma("unroll")                                                          \
    for (int q = 0; q < 4; ++q) {                                              \
      aZx = __builtin_amdgcn_mfma_f32_16x16x32_f16(wih[1][q], xb[q], aZx,0,0,0); \
      aZh = __builtin_amdgcn_mfma_f32_16x16x32_f16(whh[1][q], hb[q], aZh,0,0,0); \
    }                                                                          \
    f32x4 aRx = bRs, aRh = {0,0,0,0};                                          \
    _Pragma("unroll")                                                          \
    for (int q = 0; q < 4; ++q) {                                              \
      aRx = __builtin_amdgcn_mfma_f32_16x16x32_f16(wih[0][q], xb[q], aRx,0,0,0); \
      aRh = __builtin_amdgcn_mfma_f32_16x16x32_f16(whh[0][q], hb[q], aRh,0,0,0); \
    }                                                                          \
    float z_[4];                                                               \
    _Pragma("unroll")                                                          \
    for (int i = 0; i < 4; ++i) z_[i] = sigmoidf_(aZx[i] + aZh[i]);            \
    f32x4 aNx = bXn, aNh = bHn;                                                \
    _Pragma("unroll")                                                          \
    for (int q = 0; q < 4; ++q) {                                              \
      aNx = __builtin_amdgcn_mfma_f32_16x16x32_f16(wih[2][q], xb[q], aNx,0,0,0); \
      aNh = __builtin_amdgcn_mfma_f32_16x16x32_f16(whh[2][q], hb[q], aNh,0,0,0); \
    }                                                                          \
    float r_[4];                                                               \
    _Pragma("unroll")                                                          \
    for (int i = 0; i < 4; ++i) r_[i] = sigmoidf_(aRx[i] + aRh[i]);            \
    float hn_[4];                                                              \
    _Pragma("unroll")                                                          \
    for (int i = 0; i < 4; ++i) {                                              \
      float n = tanhf_(aNx[i] + r_[i] * aNh[i]);                               \
      float h;                                                                 \
      if (AUG) { float u = z_[i] * at_; h = hold[i] + u * (n - hold[i]); }     \
      else     { h = n + z_[i] * (hold[i] - n); }                              \
      hold[i] = h; hn_[i] = h;                                                 \
    }                                                                          \
    f16x4 hv = {(f16)hn_[0], (f16)hn_[1], (f16)hn_[2], (f16)hn_[3]};           \
    *(f16x4*)(HWRN) = hv;                                                      \
    if (!AUG) {                                                                \
      *(f16x4*)histp = hv;  histp += H;                                        \
    } else {                                                                   \
      if (t5_ == len_l - 1) {                                                  \
        f32x4 ov = {hn_[0], hn_[1], hn_[2], hn_[3]};                           \
        *(f32x4*)outpp = ov;                                                   \
      }                                                                        \
    }                                                                          \
    if (t5_ + 1 < T) {                                                         \
      if (AUG) {                                                               \
        *(f16x4*)(XSTN) = PW16;                                                \
      } else {                                                                 \
        f16x4 s4 = {(f16)PW32.x, (f16)PW32.y, (f16)PW32.z, (f16)PW32.w};       \
        *(f16x4*)(XSTN) = s4;                                                  \
      }                                                                        \
    }                                                                          \
    lds_sync();                                                                \
  }

  for (int t = 0; t < T; t += 2) {
    STEP(t,     xrd0, hrd0, hwr1, xst1, Pa32, Pb32, Pa16, Pb16, Aa, pxE32, pxE16)
    STEP(t + 1, xrd1, hrd1, hwr0, xst0, Pb32, Pa32, Pb16, Pa16, Ab, pxO32, pxO16)
  }
#undef STEP
}

// ---------------- DIN attention (MFMA version; rcp sigmoid — R10) ----------------
__global__ __launch_bounds__(256)
void attn_kernel(const float* __restrict__ query,
                 const f16*   __restrict__ hist,
                 const int*   __restrict__ mask,
                 const float* __restrict__ W1, const float* __restrict__ b1,
                 const float* __restrict__ W2, const float* __restrict__ b2,
                 float* __restrict__ attv, int T)
{
  __shared__ float qs[H];
  __shared__ f16   WqH[48 * PADW];
  __shared__ float qcp[48], w2p[48];
  __shared__ float logitsS[224];
  __shared__ float red[256];

  const int tid = threadIdx.x, b = blockIdx.x;
  const int w = tid >> 6, l = tid & 63, l16 = l & 15, lhi = l >> 4;

  if (tid < H) qs[tid] = query[b * H + tid];
  if (tid < 48) w2p[tid] = (tid < AH) ? W2[tid] : 0.f;
  __syncthreads();

  for (int i = tid; i < 48 * H; i += 256) {
    int u = i >> 7, k = i & (H - 1);
    float v = 0.f;
    if (u < AH) {
      const float* r = W1 + u * 4 * H;
      v = r[H + k] - r[2*H + k] + qs[k] * r[3*H + k];
    }
    WqH[u * PADW + k] = (f16)v;
  }
  if (tid < 48) {
    float s = 0.f;
    if (tid < AH) {
      const float* r = W1 + tid * 4 * H;
      s = b1[tid];
      for (int k = 0; k < H; ++k) s += qs[k] * (r[k] + r[2*H + k]);
    }
    qcp[tid] = s;
  }
  __syncthreads();

  const f32x4 qcv0 = *(const f32x4*)&qcp[lhi*4];
  const f32x4 qcv1 = *(const f32x4*)&qcp[16 + lhi*4];
  const f32x4 qcv2 = *(const f32x4*)&qcp[32 + lhi*4];
  const f32x4 w2v0 = *(const f32x4*)&w2p[lhi*4];
  const f32x4 w2v1 = *(const f32x4*)&w2p[16 + lhi*4];
  const f32x4 w2v2 = *(const f32x4*)&w2p[32 + lhi*4];

  const int NMT = (T + 15) >> 4;
  for (int mt = w; mt < NMT; mt += 4) {
    const int t0 = mt * 16;
    f16x8 hbf[4];
    #pragma unroll
    for (int q = 0; q < 4; ++q)
      hbf[q] = *(const f16x8*)(hist + ((size_t)b*T + t0 + l16)*H + q*32 + lhi*8);
    f32x4 d0 = {0,0,0,0}, d1 = {0,0,0,0}, d2 = {0,0,0,0};
    #pragma unroll
    for (int q = 0; q < 4; ++q) {
      f16x8 wq0 = *(const f16x8*)(&WqH[ l16       * PADW + q*32 + lhi*8]);
      f16x8 wq1 = *(const f16x8*)(&WqH[(16 + l16) * PADW + q*32 + lhi*8]);
      f16x8 wq2 = *(const f16x8*)(&WqH[(32 + l16) * PADW + q*32 + lhi*8]);
      d0 = __builtin_amdgcn_mfma_f32_16x16x32_f16(wq0, hbf[q], d0, 0,0,0);
      d1 = __builtin_amdgcn_mfma_f32_16x16x32_f16(wq1, hbf[q], d1, 0,0,0);
      d2 = __builtin_amdgcn_mfma_f32_16x16x32_f16(wq2, hbf[q], d2, 0,0,0);
    }
    float p = 0.f;
    #pragma unroll
    for (int i = 0; i < 4; ++i) {
      p += w2v0[i] * sigmoidf_(d0[i] + qcv0[i]);
      p += w2v1[i] * sigmoidf_(d1[i] + qcv1[i]);
      p += w2v2[i] * sigmoidf_(d2[i] + qcv2[i]);
    }
    p += __shfl_xor(p, 16, 64);
    p += __shfl_xor(p, 32, 64);
    if (lhi == 0) logitsS[t0 + l16] = p;
  }
  __syncthreads();

  const int t = tid;
  float logit = -1e30f; int mk = 0;
  if (t < T) {
    mk = mask[(size_t)b*T + t];
    logit = (mk > 0) ? (logitsS[t] + b2[0]) : -1e30f;
  }
  red[tid] = logit; __syncthreads();
  for (int s = 128; s > 0; s >>= 1) { if (tid < s) red[tid] = fmaxf(red[tid], red[tid+s]); __syncthreads(); }
  float mx = red[0]; __syncthreads();
  float ev = (t < T && mk > 0) ? __expf(logit - mx) : 0.f;
  red[tid] = ev; __syncthreads();
  for (int s = 128; s > 0; s >>= 1) { if (tid < s) red[tid] += red[tid+s]; __syncthreads(); }
  float sm = red[0];
  if (t < T) attv[(size_t)b*T + t] = ev * __builtin_amdgcn_rcpf(sm);
}

// ---------------- host ----------------
extern "C" void kernel_launch(void* const* d_in, const int* in_sizes, int n_in,
                              void* d_out, int out_size, void* d_ws, size_t ws_size,
                              hipStream_t stream)
{
  const float* query = (const float*)d_in[0];
  const float* ub    = (const float*)d_in[1];
  const int*   mask  = (const int*)d_in[2];
  const float* gWih  = (const float*)d_in[3];
  const float* gWhh  = (const float*)d_in[4];
  const float* gbih  = (const float*)d_in[5];
  const float* gbhh  = (const float*)d_in[6];
  const float* aW1   = (const float*)d_in[7];
  const float* ab1   = (const float*)d_in[8];
  const float* aW2   = (const float*)d_in[9];
  const float* ab2   = (const float*)d_in[10];
  const float* uWih  = (const float*)d_in[11];
  const float* uWhh  = (const float*)d_in[12];
  const float* ubih  = (const float*)d_in[13];
  const float* ubhh  = (const float*)d_in[14];

  const int B = in_sizes[0] / H;            // 1024
  const int T = in_sizes[1] / in_sizes[0];  // 200

  // workspace layout
  char*  ws   = (char*)d_ws;
  f16*   wf   = (f16*)ws;                                   // 393216 B
  int*   lenp = (int*)(ws + 393216);                        // 4096 B
  float* attb = (float*)(ws + 397312);                      // B*T*4
  f16*   hist = (f16*)(ws + 397312 + (size_t)B * 200 * 4);  // B*T*H f16

  prep_weights<<<(4 * G3 * H + 255) / 256, 256, 0, stream>>>(gWih, gWhh, uWih, uWhh, wf);
  prep_len<<<(B + 255) / 256, 256, 0, stream>>>(mask, lenp, T, B);

  scan_kernel<false><<<B / 16, 512, 0, stream>>>(
      ub, (const f16*)nullptr, wf, wf + G3 * H, gbih, gbhh,
      (const float*)nullptr, (const int*)nullptr, hist, (float*)nullptr, T);

  attn_kernel<<<B, 256, 0, stream>>>(query, hist, mask, aW1, ab1, aW2, ab2, attb, T);

  scan_kernel<true><<<B / 16, 512, 0, stream>>>(
      (const float*)nullptr, hist, wf + 2 * G3 * H, wf + 3 * G3 * H, ubih, ubhh,
      attb, lenp, (f16*)nullptr, (float*)d_out, T);
}